// Round 11
// baseline (127.102 us; speedup 1.0000x reference)
//
#include <hip/hip_runtime.h>

#define BB 1024
#define LL 200
#define HH 512
#define NOUT 5
#define NSUB 4
#define TAILB 256
#define BN_EPS 1e-5f

typedef __attribute__((ext_vector_type(8))) short bf16x8;
typedef __attribute__((ext_vector_type(4))) float f32x4;

static __device__ __forceinline__ unsigned short f2bf(float f) {
    unsigned u = __builtin_bit_cast(unsigned, f);
    unsigned r = (u + 0x7FFF + ((u >> 16) & 1)) >> 16;  // RNE
    return (unsigned short)r;
}
static __device__ __forceinline__ float bf2f(unsigned short s) {
    unsigned u = ((unsigned)s) << 16;
    return __builtin_bit_cast(float, u);
}

// Two-phase software grid barrier (256 blocks, all trivially CU-resident).
// Counters are re-zeroed each call by pool_partial (stream-ordered before
// the tail kernel), so graph replays are deterministic.
static __device__ __forceinline__ void grid_bar(int* cnt) {
    __threadfence();
    __syncthreads();
    if (threadIdx.x == 0) {
        __hip_atomic_fetch_add(cnt, 1, __ATOMIC_ACQ_REL, __HIP_MEMORY_SCOPE_AGENT);
        while (__hip_atomic_load(cnt, __ATOMIC_ACQUIRE, __HIP_MEMORY_SCOPE_AGENT) < TAILB) {}
    }
    __syncthreads();
}

// ---------------- K1: pool partials (bf16) + W1 pack on extra blocks ----
// Blocks [0,4096): bid=b*4+s gathers tokens t ≡ {2s,2s+1} (mod 8) of ex b.
// Blocks [4096,4352): pack W1 -> Bpk. Block 4096 zeroes ps/pq + barrier cnts.
__global__ __launch_bounds__(256) void pool_partial(const int* __restrict__ tokens,
                                                    const int* __restrict__ lengths,
                                                    const float* __restrict__ emb,
                                                    unsigned short* __restrict__ part,
                                                    const float* __restrict__ W1,
                                                    unsigned short* __restrict__ Bpk,
                                                    float* __restrict__ ps,
                                                    int* __restrict__ bar) {
    __shared__ int toks[LL];
    __shared__ float red[128][4];
    const int bid = blockIdx.x;
    const int tid = threadIdx.x;
    if (bid >= BB * NSUB) {  // ---- W1 fragment pack ----
        const int id = (bid - BB * NSUB) * 256 + tid;  // 65536 threads, 4 elems
        const int base = id * 4;
        const int k = base >> 9;
        const int n = base & 511;
        const float4 w = *(const float4*)&W1[(size_t)k * HH + n];
        const float wv[4] = {w.x, w.y, w.z, w.w};
#pragma unroll
        for (int i = 0; i < 4; ++i) {
            const int ni = n + i;
            const int lane = ((k >> 3) & 3) * 16 + (ni & 15);
            const size_t eidx = (((size_t)(ni >> 4) * 16 + (k >> 5)) * 64 + lane) * 8 + (k & 7);
            Bpk[eidx] = f2bf(wv[i]);
        }
        if (bid == BB * NSUB) {  // zero ps+pq (1024 floats) + barrier counters
            ((float4*)ps)[tid] = make_float4(0.f, 0.f, 0.f, 0.f);
            if (tid < 2) bar[tid] = 0;
        }
        return;
    }
    const int b = bid >> 2;
    const int s = bid & 3;
    const int len = lengths[b];
    for (int t = tid; t < len; t += 256) toks[t] = tokens[b * LL + t];
    __syncthreads();
    const int g = tid >> 7;
    const int q = tid & 127;
    const int c = q * 4;
    float ax = 0.f, ay = 0.f, az = 0.f, aw = 0.f;
    int t = s * 2 + g;
    for (; t + 56 < len; t += 64) {  // 8 independent gathers in flight
#pragma unroll
        for (int u = 0; u < 8; ++u) {
            const float4 v = *(const float4*)&emb[(size_t)toks[t + 8 * u] * HH + c];
            ax += v.x; ay += v.y; az += v.z; aw += v.w;
        }
    }
    for (; t < len; t += 8) {
        const float4 v = *(const float4*)&emb[(size_t)toks[t] * HH + c];
        ax += v.x; ay += v.y; az += v.z; aw += v.w;
    }
    if (g == 1) {
        red[q][0] = ax; red[q][1] = ay; red[q][2] = az; red[q][3] = aw;
    }
    __syncthreads();
    if (g == 0) {
        ushort4 o;
        o.x = f2bf(ax + red[q][0]);
        o.y = f2bf(ay + red[q][1]);
        o.z = f2bf(az + red[q][2]);
        o.w = f2bf(aw + red[q][3]);
        *(ushort4*)&part[(size_t)bid * HH + c] = o;
    }
}

// ---------------- K2 (fused tail): reduce_pack -> gemm+stats -> BN+out --
// 256 blocks x 256 threads, two grid barriers.
__global__ __launch_bounds__(256) void tail_kernel(const unsigned short* __restrict__ part,
                                                   const int* __restrict__ lengths,
                                                   unsigned short* __restrict__ Apk,
                                                   const unsigned short* __restrict__ Bpk,
                                                   const float* __restrict__ b1,
                                                   unsigned short* __restrict__ hpre,
                                                   float* __restrict__ ps,
                                                   float* __restrict__ pq,
                                                   const float* __restrict__ gamma,
                                                   const float* __restrict__ beta,
                                                   const float* __restrict__ W2,
                                                   const float* __restrict__ b2,
                                                   float* __restrict__ out,
                                                   int* __restrict__ bar) {
    const int bid = blockIdx.x;
    const int tid = threadIdx.x;

    // ---- Phase A: reduce bf16 partials -> Apk fragment pack (2 quads/thr)
#pragma unroll
    for (int i = 0; i < 2; ++i) {
        const int idx = bid * 512 + i * 256 + tid;  // 131072 quads total
        const int b = idx >> 7;
        const int q = idx & 127;
        const int c = q * 4;
        float s0 = 0.f, s1 = 0.f, s2 = 0.f, s3 = 0.f;
#pragma unroll
        for (int j = 0; j < 4; ++j) {
            const ushort4 p = *(const ushort4*)&part[((size_t)(b * 4 + j)) * HH + c];
            s0 += bf2f(p.x); s1 += bf2f(p.y); s2 += bf2f(p.z); s3 += bf2f(p.w);
        }
        const float inv = 1.f / (float)lengths[b];
        const int lane = ((c >> 3) & 3) * 16 + (b & 15);
        const size_t eidx = (((size_t)(b >> 4) * 16 + (c >> 5)) * 64 + lane) * 8 + (c & 7);
        ushort4 o;
        o.x = f2bf(s0 * inv); o.y = f2bf(s1 * inv);
        o.z = f2bf(s2 * inv); o.w = f2bf(s3 * inv);
        *(ushort4*)&Apk[eidx] = o;
    }
    grid_bar(&bar[0]);

    // ---- Phase B: 32x64-tile MFMA gemm + column stats ----
    {
        const int lane = tid & 63;
        const int w = tid >> 6;
        const int bx = bid & 7;    // n-block (8)
        const int by = bid >> 3;   // m-block (32)
        const int mt = by * 2 + (w >> 1);
        const int nt0 = bx * 4 + (w & 1) * 2;

        f32x4 acc0 = (f32x4){0.f, 0.f, 0.f, 0.f};
        f32x4 acc1 = (f32x4){0.f, 0.f, 0.f, 0.f};

        const unsigned short* ap = Apk + ((size_t)mt * 16 * 64 + lane) * 8;
        const unsigned short* b0p = Bpk + ((size_t)(nt0 + 0) * 16 * 64 + lane) * 8;
        const unsigned short* b1p = Bpk + ((size_t)(nt0 + 1) * 16 * 64 + lane) * 8;
#pragma unroll 4
        for (int ks = 0; ks < 16; ++ks) {
            const bf16x8 a = *(const bf16x8*)(ap + (size_t)ks * 512);
            const bf16x8 bb0 = *(const bf16x8*)(b0p + (size_t)ks * 512);
            const bf16x8 bb1 = *(const bf16x8*)(b1p + (size_t)ks * 512);
            acc0 = __builtin_amdgcn_mfma_f32_16x16x32_bf16(a, bb0, acc0, 0, 0, 0);
            acc1 = __builtin_amdgcn_mfma_f32_16x16x32_bf16(a, bb1, acc1, 0, 0, 0);
        }

        const int col0 = nt0 * 16 + (lane & 15);
        const int col1 = col0 + 16;
        const float bias0 = b1[col0];
        const float bias1 = b1[col1];
        const int rowb = mt * 16 + (lane >> 4) * 4;
        float s0 = 0.f, q0 = 0.f, s1 = 0.f, q1 = 0.f;
#pragma unroll
        for (int r = 0; r < 4; ++r) {
            const float v0 = acc0[r] + bias0;
            const float v1 = acc1[r] + bias1;
            hpre[(size_t)(rowb + r) * HH + col0] = f2bf(v0);
            hpre[(size_t)(rowb + r) * HH + col1] = f2bf(v1);
            s0 += v0; q0 += v0 * v0;
            s1 += v1; q1 += v1 * v1;
        }
        s0 += __shfl_xor(s0, 16, 64); s0 += __shfl_xor(s0, 32, 64);
        q0 += __shfl_xor(q0, 16, 64); q0 += __shfl_xor(q0, 32, 64);
        s1 += __shfl_xor(s1, 16, 64); s1 += __shfl_xor(s1, 32, 64);
        q1 += __shfl_xor(q1, 16, 64); q1 += __shfl_xor(q1, 32, 64);
        if (lane < 16) {
            atomicAdd(&ps[col0], s0);
            atomicAdd(&pq[col0], q0);
            atomicAdd(&ps[col1], s1);
            atomicAdd(&pq[col1], q1);
        }
    }
    grid_bar(&bar[1]);

    // ---- Phase C: BN finalize + ReLU + GEMM2 (wave per row) ----
    {
        const int lane = tid & 63;
        const int wave = tid >> 6;
        const int row = bid * 4 + wave;
        const int c0 = lane * 8;

        float sc[8], sh[8];
#pragma unroll
        for (int j = 0; j < 8; ++j) {
            const float mu = ps[c0 + j] * (1.f / (float)BB);
            const float var = pq[c0 + j] * (1.f / (float)BB) - mu * mu;
            const float scale = gamma[c0 + j] * rsqrtf(var + BN_EPS);
            sc[j] = scale;
            sh[j] = beta[c0 + j] - mu * scale;
        }
        float w[8][NOUT];
#pragma unroll
        for (int j = 0; j < 8; ++j)
#pragma unroll
            for (int k = 0; k < NOUT; ++k) w[j][k] = W2[(c0 + j) * NOUT + k];

        const uint4 hv = *(const uint4*)&hpre[(size_t)row * HH + c0];
        const unsigned hw[4] = {hv.x, hv.y, hv.z, hv.w};
        float a0 = 0.f, a1 = 0.f, a2 = 0.f, a3 = 0.f, a4 = 0.f;
#pragma unroll
        for (int p = 0; p < 4; ++p) {
            const float fe = __builtin_bit_cast(float, hw[p] << 16);
            const float fo = __builtin_bit_cast(float, hw[p] & 0xFFFF0000u);
            float y0 = fe * sc[2 * p] + sh[2 * p];
            float y1 = fo * sc[2 * p + 1] + sh[2 * p + 1];
            y0 = fmaxf(y0, 0.f);
            y1 = fmaxf(y1, 0.f);
            a0 += y0 * w[2 * p][0] + y1 * w[2 * p + 1][0];
            a1 += y0 * w[2 * p][1] + y1 * w[2 * p + 1][1];
            a2 += y0 * w[2 * p][2] + y1 * w[2 * p + 1][2];
            a3 += y0 * w[2 * p][3] + y1 * w[2 * p + 1][3];
            a4 += y0 * w[2 * p][4] + y1 * w[2 * p + 1][4];
        }
#pragma unroll
        for (int off = 32; off > 0; off >>= 1) {
            a0 += __shfl_down(a0, off, 64);
            a1 += __shfl_down(a1, off, 64);
            a2 += __shfl_down(a2, off, 64);
            a3 += __shfl_down(a3, off, 64);
            a4 += __shfl_down(a4, off, 64);
        }
        if (lane == 0) {
            out[row * NOUT + 0] = a0 + b2[0];
            out[row * NOUT + 1] = a1 + b2[1];
            out[row * NOUT + 2] = a2 + b2[2];
            out[row * NOUT + 3] = a3 + b2[3];
            out[row * NOUT + 4] = a4 + b2[4];
        }
    }
}

extern "C" void kernel_launch(void* const* d_in, const int* in_sizes, int n_in,
                              void* d_out, int out_size, void* d_ws, size_t ws_size,
                              hipStream_t stream) {
    const int*   tokens  = (const int*)d_in[0];
    const int*   lengths = (const int*)d_in[1];
    const float* emb     = (const float*)d_in[2];
    const float* W1      = (const float*)d_in[3];
    const float* b1      = (const float*)d_in[4];
    const float* gamma   = (const float*)d_in[5];
    const float* beta    = (const float*)d_in[6];
    const float* W2      = (const float*)d_in[7];
    const float* b2      = (const float*)d_in[8];
    float* out = (float*)d_out;

    float* ps = (float*)d_ws;                      // 512
    float* pq = ps + HH;                           // 512
    int*   bar = (int*)(pq + HH);                  // 2 (pad to 4)
    unsigned short* hpre = (unsigned short*)(bar + 4);          // 1024*512 bf16
    unsigned short* part = hpre + (size_t)BB * HH;              // 4096*512 bf16
    unsigned short* Apk  = part + (size_t)BB * NSUB * HH;       // 1024*512 bf16
    unsigned short* Bpk  = Apk + (size_t)BB * HH;               // 512*512 bf16

    pool_partial<<<BB * NSUB + 256, 256, 0, stream>>>(tokens, lengths, emb, part, W1, Bpk, ps, bar);
    tail_kernel<<<TAILB, 256, 0, stream>>>(part, lengths, Apk, Bpk, b1, hpre, ps, pq,
                                           gamma, beta, W2, b2, out, bar);
}

// Round 12
// 55.540 us; speedup vs baseline: 2.2885x; 2.2885x over previous
//
#include <hip/hip_runtime.h>

#define BB 1024
#define LL 200
#define HH 512
#define NOUT 5
#define NSUB 4
#define BN_EPS 1e-5f

typedef __attribute__((ext_vector_type(8))) short bf16x8;
typedef __attribute__((ext_vector_type(8))) unsigned short u16x8;
typedef __attribute__((ext_vector_type(4))) float f32x4;

static __device__ __forceinline__ unsigned short f2bf(float f) {
    unsigned u = __builtin_bit_cast(unsigned, f);
    unsigned r = (u + 0x7FFF + ((u >> 16) & 1)) >> 16;  // RNE
    return (unsigned short)r;
}
static __device__ __forceinline__ float bf2f(unsigned short s) {
    unsigned u = ((unsigned)s) << 16;
    return __builtin_bit_cast(float, u);
}

// ---------------- K1: pool partials (bf16) + W1 pack on extra blocks ----
// Blocks [0,4096): bid=b*4+s gathers tokens t ≡ {2s,2s+1} (mod 8) of ex b.
// Blocks [4096,4352): pack W1 -> Bpk (fills CUs idled by pool's straggler
// tail). Block 4096 zeroes ps/pq.
__global__ __launch_bounds__(256) void pool_partial(const int* __restrict__ tokens,
                                                    const int* __restrict__ lengths,
                                                    const float* __restrict__ emb,
                                                    unsigned short* __restrict__ part,
                                                    const float* __restrict__ W1,
                                                    unsigned short* __restrict__ Bpk,
                                                    float* __restrict__ ps) {
    __shared__ int toks[LL];
    __shared__ float red[128][4];
    const int bid = blockIdx.x;
    const int tid = threadIdx.x;
    if (bid >= BB * NSUB) {  // ---- W1 fragment pack ----
        const int id = (bid - BB * NSUB) * 256 + tid;  // 65536 threads, 4 elems
        const int base = id * 4;
        const int k = base >> 9;
        const int n = base & 511;
        const float4 w = *(const float4*)&W1[(size_t)k * HH + n];
        const float wv[4] = {w.x, w.y, w.z, w.w};
#pragma unroll
        for (int i = 0; i < 4; ++i) {
            const int ni = n + i;
            const int lane = ((k >> 3) & 3) * 16 + (ni & 15);
            const size_t eidx = (((size_t)(ni >> 4) * 16 + (k >> 5)) * 64 + lane) * 8 + (k & 7);
            Bpk[eidx] = f2bf(wv[i]);
        }
        if (bid == BB * NSUB) {  // zero ps+pq (1024 contiguous floats)
            ((float4*)ps)[tid] = make_float4(0.f, 0.f, 0.f, 0.f);
        }
        return;
    }
    const int b = bid >> 2;
    const int s = bid & 3;
    const int len = lengths[b];
    for (int t = tid; t < len; t += 256) toks[t] = tokens[b * LL + t];
    __syncthreads();
    const int g = tid >> 7;
    const int q = tid & 127;
    const int c = q * 4;
    float ax = 0.f, ay = 0.f, az = 0.f, aw = 0.f;
    int t = s * 2 + g;
    for (; t + 56 < len; t += 64) {  // 8 independent gathers in flight
#pragma unroll
        for (int u = 0; u < 8; ++u) {
            const float4 v = *(const float4*)&emb[(size_t)toks[t + 8 * u] * HH + c];
            ax += v.x; ay += v.y; az += v.z; aw += v.w;
        }
    }
    for (; t < len; t += 8) {
        const float4 v = *(const float4*)&emb[(size_t)toks[t] * HH + c];
        ax += v.x; ay += v.y; az += v.z; aw += v.w;
    }
    if (g == 1) {
        red[q][0] = ax; red[q][1] = ay; red[q][2] = az; red[q][3] = aw;
    }
    __syncthreads();
    if (g == 0) {
        ushort4 o;
        o.x = f2bf(ax + red[q][0]);
        o.y = f2bf(ay + red[q][1]);
        o.z = f2bf(az + red[q][2]);
        o.w = f2bf(aw + red[q][3]);
        *(ushort4*)&part[(size_t)bid * HH + c] = o;
    }
}

// ---------------- K2: gemm with in-register A-fragment build -----------
// 32x64 tile -> grid (8,32) = 256 blocks. Lane's A-fragment has FIXED
// row = mt*16+(lane&15), k-slot base kb = lane>>4: per kstep, 4 ushort8
// partial loads -> f32 sum -> *inv_len -> bf16 (bit-identical to the old
// reduce_pack math). B from packed Bpk. Fused column stats.
__global__ __launch_bounds__(256) void gemm1_fused(const unsigned short* __restrict__ part,
                                                   const int* __restrict__ lengths,
                                                   const unsigned short* __restrict__ Bpk,
                                                   const float* __restrict__ b1,
                                                   unsigned short* __restrict__ hpre,
                                                   float* __restrict__ ps,
                                                   float* __restrict__ pq) {
    const int tid = threadIdx.x;
    const int lane = tid & 63;
    const int w = tid >> 6;
    const int mt = blockIdx.y * 2 + (w >> 1);
    const int nt0 = blockIdx.x * 4 + (w & 1) * 2;

    const int rloc = lane & 15;
    const int kb = lane >> 4;          // 0..3
    const int row = mt * 16 + rloc;
    const float inv = 1.f / (float)lengths[row];
    const unsigned short* p0 = part + ((size_t)(row * 4 + 0)) * HH + kb * 8;
    const unsigned short* p1 = part + ((size_t)(row * 4 + 1)) * HH + kb * 8;
    const unsigned short* p2 = part + ((size_t)(row * 4 + 2)) * HH + kb * 8;
    const unsigned short* p3 = part + ((size_t)(row * 4 + 3)) * HH + kb * 8;

    f32x4 acc0 = (f32x4){0.f, 0.f, 0.f, 0.f};
    f32x4 acc1 = (f32x4){0.f, 0.f, 0.f, 0.f};

    const unsigned short* b0p = Bpk + ((size_t)(nt0 + 0) * 16 * 64 + lane) * 8;
    const unsigned short* b1p = Bpk + ((size_t)(nt0 + 1) * 16 * 64 + lane) * 8;
#pragma unroll 4
    for (int ks = 0; ks < 16; ++ks) {
        const int off = ks * 32;
        const u16x8 q0 = *(const u16x8*)(p0 + off);
        const u16x8 q1 = *(const u16x8*)(p1 + off);
        const u16x8 q2 = *(const u16x8*)(p2 + off);
        const u16x8 q3 = *(const u16x8*)(p3 + off);
        bf16x8 a;
#pragma unroll
        for (int i = 0; i < 8; ++i) {
            const float v = (bf2f(q0[i]) + bf2f(q1[i])) + (bf2f(q2[i]) + bf2f(q3[i]));
            a[i] = (short)f2bf(v * inv);
        }
        const bf16x8 bb0 = *(const bf16x8*)(b0p + (size_t)ks * 512);
        const bf16x8 bb1 = *(const bf16x8*)(b1p + (size_t)ks * 512);
        acc0 = __builtin_amdgcn_mfma_f32_16x16x32_bf16(a, bb0, acc0, 0, 0, 0);
        acc1 = __builtin_amdgcn_mfma_f32_16x16x32_bf16(a, bb1, acc1, 0, 0, 0);
    }

    const int col0 = nt0 * 16 + (lane & 15);
    const int col1 = col0 + 16;
    const float bias0 = b1[col0];
    const float bias1 = b1[col1];
    const int rowb = mt * 16 + (lane >> 4) * 4;
    float s0 = 0.f, q0v = 0.f, s1 = 0.f, q1v = 0.f;
#pragma unroll
    for (int r = 0; r < 4; ++r) {
        const float v0 = acc0[r] + bias0;
        const float v1 = acc1[r] + bias1;
        hpre[(size_t)(rowb + r) * HH + col0] = f2bf(v0);
        hpre[(size_t)(rowb + r) * HH + col1] = f2bf(v1);
        s0 += v0; q0v += v0 * v0;
        s1 += v1; q1v += v1 * v1;
    }
    s0 += __shfl_xor(s0, 16, 64); s0 += __shfl_xor(s0, 32, 64);
    q0v += __shfl_xor(q0v, 16, 64); q0v += __shfl_xor(q0v, 32, 64);
    s1 += __shfl_xor(s1, 16, 64); s1 += __shfl_xor(s1, 32, 64);
    q1v += __shfl_xor(q1v, 16, 64); q1v += __shfl_xor(q1v, 32, 64);
    if (lane < 16) {
        atomicAdd(&ps[col0], s0);
        atomicAdd(&pq[col0], q0v);
        atomicAdd(&ps[col1], s1);
        atomicAdd(&pq[col1], q1v);
    }
}

// ---------------- K3: BN finalize + ReLU + GEMM2 -----------------------
// Wave per row; lane owns 8 CONSECUTIVE cols -> one uint4 (16B) row read.
__global__ __launch_bounds__(256) void bn_out_kernel(const unsigned short* __restrict__ Hm,
                                                     const float* __restrict__ ps,
                                                     const float* __restrict__ pq,
                                                     const float* __restrict__ gamma,
                                                     const float* __restrict__ beta,
                                                     const float* __restrict__ W2,
                                                     const float* __restrict__ b2,
                                                     float* __restrict__ out) {
    const int tid = threadIdx.x;
    const int lane = tid & 63;
    const int wave = tid >> 6;
    const int row = blockIdx.x * 4 + wave;
    const int c0 = lane * 8;

    float sc[8], sh[8];
#pragma unroll
    for (int j = 0; j < 8; ++j) {
        const float mu = ps[c0 + j] * (1.f / (float)BB);
        const float var = pq[c0 + j] * (1.f / (float)BB) - mu * mu;
        const float scale = gamma[c0 + j] * rsqrtf(var + BN_EPS);
        sc[j] = scale;
        sh[j] = beta[c0 + j] - mu * scale;
    }
    float w[8][NOUT];
#pragma unroll
    for (int j = 0; j < 8; ++j)
#pragma unroll
        for (int k = 0; k < NOUT; ++k) w[j][k] = W2[(c0 + j) * NOUT + k];

    const uint4 hv = *(const uint4*)&Hm[(size_t)row * HH + c0];
    const unsigned hw[4] = {hv.x, hv.y, hv.z, hv.w};
    float a0 = 0.f, a1 = 0.f, a2 = 0.f, a3 = 0.f, a4 = 0.f;
#pragma unroll
    for (int p = 0; p < 4; ++p) {
        const float fe = __builtin_bit_cast(float, hw[p] << 16);
        const float fo = __builtin_bit_cast(float, hw[p] & 0xFFFF0000u);
        float y0 = fe * sc[2 * p] + sh[2 * p];
        float y1 = fo * sc[2 * p + 1] + sh[2 * p + 1];
        y0 = fmaxf(y0, 0.f);
        y1 = fmaxf(y1, 0.f);
        a0 += y0 * w[2 * p][0] + y1 * w[2 * p + 1][0];
        a1 += y0 * w[2 * p][1] + y1 * w[2 * p + 1][1];
        a2 += y0 * w[2 * p][2] + y1 * w[2 * p + 1][2];
        a3 += y0 * w[2 * p][3] + y1 * w[2 * p + 1][3];
        a4 += y0 * w[2 * p][4] + y1 * w[2 * p + 1][4];
    }
#pragma unroll
    for (int off = 32; off > 0; off >>= 1) {
        a0 += __shfl_down(a0, off, 64);
        a1 += __shfl_down(a1, off, 64);
        a2 += __shfl_down(a2, off, 64);
        a3 += __shfl_down(a3, off, 64);
        a4 += __shfl_down(a4, off, 64);
    }
    if (lane == 0) {
        out[row * NOUT + 0] = a0 + b2[0];
        out[row * NOUT + 1] = a1 + b2[1];
        out[row * NOUT + 2] = a2 + b2[2];
        out[row * NOUT + 3] = a3 + b2[3];
        out[row * NOUT + 4] = a4 + b2[4];
    }
}

extern "C" void kernel_launch(void* const* d_in, const int* in_sizes, int n_in,
                              void* d_out, int out_size, void* d_ws, size_t ws_size,
                              hipStream_t stream) {
    const int*   tokens  = (const int*)d_in[0];
    const int*   lengths = (const int*)d_in[1];
    const float* emb     = (const float*)d_in[2];
    const float* W1      = (const float*)d_in[3];
    const float* b1      = (const float*)d_in[4];
    const float* gamma   = (const float*)d_in[5];
    const float* beta    = (const float*)d_in[6];
    const float* W2      = (const float*)d_in[7];
    const float* b2      = (const float*)d_in[8];
    float* out = (float*)d_out;

    float* ps = (float*)d_ws;                      // 512
    float* pq = ps + HH;                           // 512
    unsigned short* hpre = (unsigned short*)(pq + HH);          // 1024*512 bf16
    unsigned short* part = hpre + (size_t)BB * HH;              // 4096*512 bf16
    unsigned short* Bpk  = part + (size_t)BB * NSUB * HH;       // 512*512 bf16

    pool_partial<<<BB * NSUB + 256, 256, 0, stream>>>(tokens, lengths, emb, part, W1, Bpk, ps);
    gemm1_fused<<<dim3(HH / 64, BB / 32), 256, 0, stream>>>(part, lengths, Bpk, b1, hpre, ps, pq);
    bn_out_kernel<<<BB / 4, 256, 0, stream>>>(hpre, ps, pq, gamma, beta, W2, b2, out);
}

// Round 13
// 50.412 us; speedup vs baseline: 2.5213x; 1.1017x over previous
//
#include <hip/hip_runtime.h>

#define BB 1024
#define LL 200
#define HH 512
#define NOUT 5
#define NSUB 4
#define BN_EPS 1e-5f

typedef __attribute__((ext_vector_type(8))) short bf16x8;
typedef __attribute__((ext_vector_type(4))) float f32x4;

static __device__ __forceinline__ unsigned short f2bf(float f) {
    unsigned u = __builtin_bit_cast(unsigned, f);
    unsigned r = (u + 0x7FFF + ((u >> 16) & 1)) >> 16;  // RNE
    return (unsigned short)r;
}
static __device__ __forceinline__ float bf2f(unsigned short s) {
    unsigned u = ((unsigned)s) << 16;
    return __builtin_bit_cast(float, u);
}

// ---------------- K1: pool partials (bf16) + W1 pack on extra blocks ----
// Blocks [0,4096): bid=b*4+s gathers tokens t ≡ {2s,2s+1} (mod 8) of ex b.
// Blocks [4096,4352): pack W1 -> Bpk (independent work; fills CUs idled by
// pool's straggler tail). Block 4096 also zeroes ps/pq.
__global__ __launch_bounds__(256) void pool_partial(const int* __restrict__ tokens,
                                                    const int* __restrict__ lengths,
                                                    const float* __restrict__ emb,
                                                    unsigned short* __restrict__ part,
                                                    const float* __restrict__ W1,
                                                    unsigned short* __restrict__ Bpk,
                                                    float* __restrict__ ps) {
    __shared__ int toks[LL];
    __shared__ float red[128][4];
    const int bid = blockIdx.x;
    const int tid = threadIdx.x;
    if (bid >= BB * NSUB) {  // ---- W1 fragment pack ----
        const int id = (bid - BB * NSUB) * 256 + tid;  // 65536 threads, 4 elems
        const int base = id * 4;
        const int k = base >> 9;
        const int n = base & 511;
        const float4 w = *(const float4*)&W1[(size_t)k * HH + n];
        const float wv[4] = {w.x, w.y, w.z, w.w};
#pragma unroll
        for (int i = 0; i < 4; ++i) {
            const int ni = n + i;
            const int lane = ((k >> 3) & 3) * 16 + (ni & 15);
            const size_t eidx = (((size_t)(ni >> 4) * 16 + (k >> 5)) * 64 + lane) * 8 + (k & 7);
            Bpk[eidx] = f2bf(wv[i]);
        }
        if (bid == BB * NSUB) {  // zero ps+pq (1024 contiguous floats)
            ((float4*)ps)[tid] = make_float4(0.f, 0.f, 0.f, 0.f);
        }
        return;
    }
    const int b = bid >> 2;
    const int s = bid & 3;
    const int len = lengths[b];
    for (int t = tid; t < len; t += 256) toks[t] = tokens[b * LL + t];
    __syncthreads();
    const int g = tid >> 7;
    const int q = tid & 127;
    const int c = q * 4;
    float ax = 0.f, ay = 0.f, az = 0.f, aw = 0.f;
    int t = s * 2 + g;
    for (; t + 56 < len; t += 64) {  // 8 independent gathers in flight
#pragma unroll
        for (int u = 0; u < 8; ++u) {
            const float4 v = *(const float4*)&emb[(size_t)toks[t + 8 * u] * HH + c];
            ax += v.x; ay += v.y; az += v.z; aw += v.w;
        }
    }
    for (; t < len; t += 8) {
        const float4 v = *(const float4*)&emb[(size_t)toks[t] * HH + c];
        ax += v.x; ay += v.y; az += v.z; aw += v.w;
    }
    if (g == 1) {
        red[q][0] = ax; red[q][1] = ay; red[q][2] = az; red[q][3] = aw;
    }
    __syncthreads();
    if (g == 0) {
        ushort4 o;
        o.x = f2bf(ax + red[q][0]);
        o.y = f2bf(ay + red[q][1]);
        o.z = f2bf(az + red[q][2]);
        o.w = f2bf(aw + red[q][3]);
        *(ushort4*)&part[(size_t)bid * HH + c] = o;
    }
}

// ---------------- K2: reduce bf16 partials -> Apk fragment pack --------
__global__ __launch_bounds__(256) void reduce_pack(const unsigned short* __restrict__ part,
                                                   const int* __restrict__ lengths,
                                                   unsigned short* __restrict__ Apk) {
    const int idx = blockIdx.x * 256 + threadIdx.x;  // 131072 = 1024 ex * 128 quads
    const int b = idx >> 7;
    const int q = idx & 127;
    const int c = q * 4;
    float s0 = 0.f, s1 = 0.f, s2 = 0.f, s3 = 0.f;
#pragma unroll
    for (int i = 0; i < 4; ++i) {
        const ushort4 p = *(const ushort4*)&part[((size_t)(b * 4 + i)) * HH + c];
        s0 += bf2f(p.x); s1 += bf2f(p.y); s2 += bf2f(p.z); s3 += bf2f(p.w);
    }
    const float inv = 1.f / (float)lengths[b];
    const int lane = ((c >> 3) & 3) * 16 + (b & 15);
    const size_t eidx = (((size_t)(b >> 4) * 16 + (c >> 5)) * 64 + lane) * 8 + (c & 7);
    ushort4 o;
    o.x = f2bf(s0 * inv); o.y = f2bf(s1 * inv);
    o.z = f2bf(s2 * inv); o.w = f2bf(s3 * inv);
    *(ushort4*)&Apk[eidx] = o;
}

// ---------------- K3: h = A@W1 + b1 via MFMA, fused column stats -------
// 32x64 tile -> grid (8,32) = 256 blocks. hpre stored bf16; stats in f32.
__global__ __launch_bounds__(256) void gemm1_mfma(const unsigned short* __restrict__ Apk,
                                                  const unsigned short* __restrict__ Bpk,
                                                  const float* __restrict__ b1,
                                                  unsigned short* __restrict__ hpre,
                                                  float* __restrict__ ps,
                                                  float* __restrict__ pq) {
    const int tid = threadIdx.x;
    const int lane = tid & 63;
    const int w = tid >> 6;
    const int mt = blockIdx.y * 2 + (w >> 1);
    const int nt0 = blockIdx.x * 4 + (w & 1) * 2;

    f32x4 acc0 = (f32x4){0.f, 0.f, 0.f, 0.f};
    f32x4 acc1 = (f32x4){0.f, 0.f, 0.f, 0.f};

    const unsigned short* ap = Apk + ((size_t)mt * 16 * 64 + lane) * 8;
    const unsigned short* b0p = Bpk + ((size_t)(nt0 + 0) * 16 * 64 + lane) * 8;
    const unsigned short* b1p = Bpk + ((size_t)(nt0 + 1) * 16 * 64 + lane) * 8;
#pragma unroll 4
    for (int ks = 0; ks < 16; ++ks) {
        const bf16x8 a = *(const bf16x8*)(ap + (size_t)ks * 512);
        const bf16x8 bb0 = *(const bf16x8*)(b0p + (size_t)ks * 512);
        const bf16x8 bb1 = *(const bf16x8*)(b1p + (size_t)ks * 512);
        acc0 = __builtin_amdgcn_mfma_f32_16x16x32_bf16(a, bb0, acc0, 0, 0, 0);
        acc1 = __builtin_amdgcn_mfma_f32_16x16x32_bf16(a, bb1, acc1, 0, 0, 0);
    }

    const int col0 = nt0 * 16 + (lane & 15);
    const int col1 = col0 + 16;
    const float bias0 = b1[col0];
    const float bias1 = b1[col1];
    const int rowb = mt * 16 + (lane >> 4) * 4;
    float s0 = 0.f, q0 = 0.f, s1 = 0.f, q1 = 0.f;
#pragma unroll
    for (int r = 0; r < 4; ++r) {
        const float v0 = acc0[r] + bias0;
        const float v1 = acc1[r] + bias1;
        hpre[(size_t)(rowb + r) * HH + col0] = f2bf(v0);
        hpre[(size_t)(rowb + r) * HH + col1] = f2bf(v1);
        s0 += v0; q0 += v0 * v0;
        s1 += v1; q1 += v1 * v1;
    }
    s0 += __shfl_xor(s0, 16, 64); s0 += __shfl_xor(s0, 32, 64);
    q0 += __shfl_xor(q0, 16, 64); q0 += __shfl_xor(q0, 32, 64);
    s1 += __shfl_xor(s1, 16, 64); s1 += __shfl_xor(s1, 32, 64);
    q1 += __shfl_xor(q1, 16, 64); q1 += __shfl_xor(q1, 32, 64);
    if (lane < 16) {
        atomicAdd(&ps[col0], s0);
        atomicAdd(&pq[col0], q0);
        atomicAdd(&ps[col1], s1);
        atomicAdd(&pq[col1], q1);
    }
}

// ---------------- K4: BN finalize + ReLU + GEMM2 -----------------------
// Wave per row; lane owns 8 CONSECUTIVE cols -> one uint4 (16B) row read.
// scale/shift recomputed per thread from ps/pq (L1/L2-hot, no LDS).
__global__ __launch_bounds__(256) void bn_out_kernel(const unsigned short* __restrict__ Hm,
                                                     const float* __restrict__ ps,
                                                     const float* __restrict__ pq,
                                                     const float* __restrict__ gamma,
                                                     const float* __restrict__ beta,
                                                     const float* __restrict__ W2,
                                                     const float* __restrict__ b2,
                                                     float* __restrict__ out) {
    const int tid = threadIdx.x;
    const int lane = tid & 63;
    const int wave = tid >> 6;
    const int row = blockIdx.x * 4 + wave;
    const int c0 = lane * 8;

    float sc[8], sh[8];
#pragma unroll
    for (int j = 0; j < 8; ++j) {
        const float mu = ps[c0 + j] * (1.f / (float)BB);
        const float var = pq[c0 + j] * (1.f / (float)BB) - mu * mu;
        const float scale = gamma[c0 + j] * rsqrtf(var + BN_EPS);
        sc[j] = scale;
        sh[j] = beta[c0 + j] - mu * scale;
    }
    float w[8][NOUT];
#pragma unroll
    for (int j = 0; j < 8; ++j)
#pragma unroll
        for (int k = 0; k < NOUT; ++k) w[j][k] = W2[(c0 + j) * NOUT + k];

    const uint4 hv = *(const uint4*)&Hm[(size_t)row * HH + c0];
    const unsigned hw[4] = {hv.x, hv.y, hv.z, hv.w};
    float a0 = 0.f, a1 = 0.f, a2 = 0.f, a3 = 0.f, a4 = 0.f;
#pragma unroll
    for (int p = 0; p < 4; ++p) {
        const float fe = __builtin_bit_cast(float, hw[p] << 16);            // elem 2p
        const float fo = __builtin_bit_cast(float, hw[p] & 0xFFFF0000u);    // elem 2p+1
        float y0 = fe * sc[2 * p] + sh[2 * p];
        float y1 = fo * sc[2 * p + 1] + sh[2 * p + 1];
        y0 = fmaxf(y0, 0.f);
        y1 = fmaxf(y1, 0.f);
        a0 += y0 * w[2 * p][0] + y1 * w[2 * p + 1][0];
        a1 += y0 * w[2 * p][1] + y1 * w[2 * p + 1][1];
        a2 += y0 * w[2 * p][2] + y1 * w[2 * p + 1][2];
        a3 += y0 * w[2 * p][3] + y1 * w[2 * p + 1][3];
        a4 += y0 * w[2 * p][4] + y1 * w[2 * p + 1][4];
    }
#pragma unroll
    for (int off = 32; off > 0; off >>= 1) {
        a0 += __shfl_down(a0, off, 64);
        a1 += __shfl_down(a1, off, 64);
        a2 += __shfl_down(a2, off, 64);
        a3 += __shfl_down(a3, off, 64);
        a4 += __shfl_down(a4, off, 64);
    }
    if (lane == 0) {
        out[row * NOUT + 0] = a0 + b2[0];
        out[row * NOUT + 1] = a1 + b2[1];
        out[row * NOUT + 2] = a2 + b2[2];
        out[row * NOUT + 3] = a3 + b2[3];
        out[row * NOUT + 4] = a4 + b2[4];
    }
}

extern "C" void kernel_launch(void* const* d_in, const int* in_sizes, int n_in,
                              void* d_out, int out_size, void* d_ws, size_t ws_size,
                              hipStream_t stream) {
    const int*   tokens  = (const int*)d_in[0];
    const int*   lengths = (const int*)d_in[1];
    const float* emb     = (const float*)d_in[2];
    const float* W1      = (const float*)d_in[3];
    const float* b1      = (const float*)d_in[4];
    const float* gamma   = (const float*)d_in[5];
    const float* beta    = (const float*)d_in[6];
    const float* W2      = (const float*)d_in[7];
    const float* b2      = (const float*)d_in[8];
    float* out = (float*)d_out;

    float* ps = (float*)d_ws;                      // 512
    float* pq = ps + HH;                           // 512
    unsigned short* hpre = (unsigned short*)(pq + HH);          // 1024*512 bf16
    unsigned short* part = hpre + (size_t)BB * HH;              // 4096*512 bf16
    unsigned short* Apk  = part + (size_t)BB * NSUB * HH;       // 1024*512 bf16
    unsigned short* Bpk  = Apk + (size_t)BB * HH;               // 512*512 bf16

    pool_partial<<<BB * NSUB + 256, 256, 0, stream>>>(tokens, lengths, emb, part, W1, Bpk, ps);
    reduce_pack<<<512, 256, 0, stream>>>(part, lengths, Apk);
    gemm1_mfma<<<dim3(HH / 64, BB / 32), 256, 0, stream>>>(Apk, Bpk, b1, hpre, ps, pq);
    bn_out_kernel<<<BB / 4, 256, 0, stream>>>(hpre, ps, pq, gamma, beta, W2, b2, out);
}